// Round 15
// baseline (212.324 us; speedup 1.0000x reference)
//
#include <hip/hip_runtime.h>
#include <math.h>

#define NN 65536
#define NE 1048576
#define KH 48
#define G3 144
#define DEGB 512
#define PREPB 15
#define E1B 1024      // edge-scan blocks (NE/4/256)
#define SB2 81        // staging blocks at head of k_edges2 (20736 ids)
#define GIB 2         // gi0p blocks at head of k_acc1

#define CAP_L1 8192
#define CAP_S1 4096
#define CAP_E2 65536
#define CAP_S2 8192

// ws byte offsets. First 524352 bytes (mark1|mark2|cnt) are zeroed by one
// hipMemsetAsync in kernel_launch.
#define OFF_MARK1  0u        // NN i32
#define OFF_MARK2  262144u   // NN i32
#define OFF_CNT    524288u   // 16 u32
#define OFF_L1R    524352u   // CAP_L1 i32
#define OFF_L1W    557120u   // CAP_L1 f32
#define OFF_S1G    589888u   // CAP_S1 i32
#define OFF_E2R    606272u   // CAP_E2 i32
#define OFF_E2S    868416u   // CAP_E2 i32
#define OFF_E2W    1130560u  // CAP_E2 f32
#define OFF_S2     1392704u  // CAP_S2 i32
#define OFF_DEG2   1425472u  // CAP_S2 f32
#define OFF_STATE  1458240u  // CAP_S2*48 f32
#define OFF_X1     3031104u  // CAP_S1*48 f32
#define OFF_TPSF   3817536u  // 128 f32
#define OFF_WHH16  3818048u  // fp16 dWhh, 288-thread h8 layout: 15552 h4 = 124416 B
#define OFF_GI0P   3947072u  // 432 f32
#define OFF_GIP    3948800u  // 20*144 f32
#define OFF_GIF    3960320u  // 40*144 f32
#define OFF_DWH4   3983360u  // 18*288 float4 (f32 dWih[:, :48], 288-thr layout) = 82944 B

typedef _Float16 h2_t __attribute__((ext_vector_type(2)));
typedef _Float16 h4_t __attribute__((ext_vector_type(4)));
typedef _Float16 h8_t __attribute__((ext_vector_type(8)));

// fast gates: v_exp_f32-based; error ~1e-6 rel, negligible vs fp16 weights
__device__ __forceinline__ float sigmf(float x) { return 1.0f / (1.0f + __expf(-x)); }
__device__ __forceinline__ float tanhfast(float x) {
    float e = __expf(2.0f * x);
    return 1.0f - 2.0f / (e + 1.0f);
}

#if __has_builtin(__builtin_amdgcn_fdot2)
__device__ __forceinline__ float fdot2f(h2_t a, h2_t b, float c) {
    return __builtin_amdgcn_fdot2(a, b, c, false);
}
#else
__device__ __forceinline__ float fdot2f(h2_t a, h2_t b, float c) {
    return c + (float)a.x * (float)b.x + (float)a.y * (float)b.y;
}
#endif

// -------- inline compaction (replaces old k_compact1/k_compact2) ----------
__device__ __forceinline__ void s2_append(int r, unsigned* cnt, int* mark2,
                                          int* s2, float* deg2) {
    if (mark2[r] != 0) return;            // benign stale-0 race: extra slot
    unsigned idx = atomicAdd(&cnt[3], 1u);
    if (idx >= CAP_S2) return;
    int old = atomicCAS(&mark2[r], 0, (int)idx + 1);
    deg2[idx] = 1.0f;
    s2[idx] = (old == 0) ? r : -1;        // -1: wasted slot, worker skips
}

__device__ __forceinline__ void s1_claim(int r, unsigned* cnt, int* mark1,
                                         int* mark2, int* s1g,
                                         int* e2r, int* e2s, float* e2w,
                                         float* x1, const float* g1b,
                                         int* s2, float* deg2) {
    if (mark1[r] != 0) return;
    unsigned idx = atomicAdd(&cnt[1], 1u);
    if (idx >= CAP_S1) return;
    int old = atomicCAS(&mark1[r], 0, (int)idx + 1);
    if (old != 0) return;                 // lost race; s1g[idx] stale, unread
    s1g[idx] = r;
    unsigned t2 = atomicAdd(&cnt[2], 1u); // self-loop E2 entry
    if (t2 < CAP_E2) { e2r[t2] = r; e2s[t2] = (int)idx; e2w[t2] = 1.0f; }
    for (int k = 0; k < KH; ++k) x1[idx * KH + k] = g1b[k];
    s2_append(r, cnt, mark2, s2, deg2);
}

// ---------------- K1: edges into node 0 + inline S1 compaction + prep ------
__global__ void k_edges1(const int* ei, const float* ew,
                         int* mark1, int* mark2, unsigned* cnt,
                         int* l1r, float* l1w, int* s1g,
                         int* e2r, int* e2s, float* e2w,
                         float* x1, const float* g1b, int* s2, float* deg2,
                         const float* past, const float* future,
                         const float* cpw, const float* cpb,
                         const float* cfw, const float* cfb,
                         const float* epWih, const float* epbih,
                         const float* efWih, const float* efbih,
                         float* giP, float* giF) {
    if (blockIdx.x >= E1B) {
        int p = blockIdx.x - E1B;   // 0..14
        const float* xs; const float* cw; const float* cb;
        const float* Wih; const float* bih; float* gout;
        int T, s0;
        if (p < 5) { xs = past;   cw = cpw; cb = cpb; Wih = epWih; bih = epbih;
                     gout = giP; T = 20; s0 = p * 4; }
        else       { xs = future; cw = cfw; cb = cfb; Wih = efWih; bih = efbih;
                     gout = giF; T = 40; s0 = (p - 5) * 4; }
        __shared__ __align__(16) float s_x[80];
        __shared__ __align__(16) float s_e[4 * KH];
        int t = threadIdx.x;
        if (t < T * 2) s_x[t] = xs[t];
        __syncthreads();
        for (int idx = t; idx < 4 * KH; idx += 256) {
            int lt = idx / KH;
            int k = idx - lt * KH;
            int tt = s0 + lt;
            float acc = cb[k];
#pragma unroll
            for (int d = 0; d < 3; ++d) {
                int tau = tt + d - 1;
                if (tau >= 0 && tau < T) {
                    acc += cw[k * 6 + d] * s_x[tau * 2 + 0];
                    acc += cw[k * 6 + 3 + d] * s_x[tau * 2 + 1];
                }
            }
            s_e[lt * KH + k] = fmaxf(acc, 0.0f);
        }
        __syncthreads();
        for (int idx = t; idx < 4 * G3; idx += 256) {
            int lt = idx / G3;
            int row = idx - lt * G3;
            const float4* wp = reinterpret_cast<const float4*>(Wih + row * KH);
            const float4* em = reinterpret_cast<const float4*>(s_e + lt * KH);
            float g = bih[row];
#pragma unroll
            for (int j = 0; j < 12; ++j) {
                float4 w4 = wp[j]; float4 e4 = em[j];
                g += w4.x * e4.x + w4.y * e4.y + w4.z * e4.z + w4.w * e4.w;
            }
            gout[(s0 + lt) * G3 + row] = g;
        }
        return;
    }
    int q = blockIdx.x * blockDim.x + threadIdx.x;
    if (q == 0)   // node 0 always in S1
        s1_claim(0, cnt, mark1, mark2, s1g, e2r, e2s, e2w, x1, g1b, s2, deg2);
    int4 c4 = reinterpret_cast<const int4*>(ei + NE)[q];
    int e = q * 4;
    int cc[4] = {c4.x, c4.y, c4.z, c4.w};
#pragma unroll
    for (int j = 0; j < 4; ++j) {
        if (cc[j] == 0) {
            int r = ei[e + j];
            float w = ew[e + j];
            unsigned s = atomicAdd(&cnt[0], 1u);
            if (s < CAP_L1) { l1r[s] = r; l1w[s] = w; }
            s1_claim(r, cnt, mark1, mark2, s1g, e2r, e2s, e2w, x1, g1b, s2, deg2);
        }
    }
}

// ---------------- K2: edges into S1 + inline S2 compaction + weight staging
__global__ void k_edges2(const int* ei, const float* ew,
                         const int* mark1, int* mark2, unsigned* cnt,
                         int* e2r, int* e2s, float* e2w, int* s2, float* deg2,
                         const float* dWhh, const float* dWih,
                         _Float16* whh16, float* dwh4) {
    if (blockIdx.x < SB2) {
        int id = blockIdx.x * blockDim.x + threadIdx.x;
        if (id < 27 * 288 * 2) {
            int pid = id >> 1, half = id & 1;
            int c = pid / 288, t = pid - c * 288;
            int k = t >> 1, hf = t & 1;
            int g = c / 9, u = c - g * 9;
            const float* src = dWhh + (size_t)(g * G3 + k) * G3
                               + hf * 72 + 8 * u + 4 * half;
            float4 f = *reinterpret_cast<const float4*>(src);
            h4_t o;
            o.x = (_Float16)f.x; o.y = (_Float16)f.y;
            o.z = (_Float16)f.z; o.w = (_Float16)f.w;
            reinterpret_cast<h4_t*>(whh16)[2 * pid + half] = o;
            return;
        }
        int id2 = id - 27 * 288 * 2;
        if (id2 < 18 * 288) {
            int c = id2 / 288, t = id2 - c * 288;
            int k = t >> 1, hf = t & 1;
            int g = c / 6, j = c - g * 6;
            const float* src = dWih + (size_t)(g * G3 + k) * G3 + hf * 24 + 4 * j;
            reinterpret_cast<float4*>(dwh4)[id2] =
                *reinterpret_cast<const float4*>(src);
        }
        return;
    }
    int q = (blockIdx.x - SB2) * blockDim.x + threadIdx.x;
    if (q >= NE / 4) return;
    int4 c4 = reinterpret_cast<const int4*>(ei + NE)[q];
    int e = q * 4;
    int cc[4] = {c4.x, c4.y, c4.z, c4.w};
#pragma unroll
    for (int j = 0; j < 4; ++j) {
        int m = mark1[cc[j]];
        if (m > 0) {
            int r = ei[e + j];
            float w = ew[e + j];
            unsigned s = atomicAdd(&cnt[2], 1u);
            if (s < CAP_E2) { e2r[s] = r; e2s[s] = m - 1; e2w[s] = w; }
            s2_append(r, cnt, mark2, s2, deg2);
        }
    }
}

// ---------------- conv1d(pad=1,k=3) + GRU over one sequence (S2 path) ------
__device__ void gru_seq(const float* xseq, int T,
                        const float* cw, const float* cb,
                        const float* Wih, const float* Whh,
                        const float* bih, const float* bhh,
                        float* out48,
                        float* s_x, float* s_embed, float* s_giA,
                        float* s_h /* [2][KH] */) {
    int t = threadIdx.x;
    int nt = blockDim.x;
    for (int i = t; i < T * 2; i += nt) s_x[i] = xseq[i];
    __syncthreads();
    for (int idx = t; idx < T * KH; idx += nt) {
        int tt = idx / KH;
        int k = idx - tt * KH;
        float acc = cb[k];
#pragma unroll
        for (int d = 0; d < 3; ++d) {
            int tau = tt + d - 1;
            if (tau >= 0 && tau < T) {
                acc += cw[k * 6 + d] * s_x[tau * 2 + 0];
                acc += cw[k * 6 + 3 + d] * s_x[tau * 2 + 1];
            }
        }
        s_embed[tt * KH + k] = fmaxf(acc, 0.0f);
    }
    __syncthreads();
    for (int idx = t; idx < T * G3; idx += nt) {
        int step = idx / G3;
        int row = idx - step * G3;
        const float4* wp = reinterpret_cast<const float4*>(Wih + row * KH);
        const float4* em = reinterpret_cast<const float4*>(s_embed + step * KH);
        float g = bih[row];
#pragma unroll
        for (int j = 0; j < 12; ++j) {
            float4 w4 = wp[j]; float4 e4 = em[j];
            g += w4.x * e4.x + w4.y * e4.y + w4.z * e4.z + w4.w * e4.w;
        }
        s_giA[idx] = g;
    }
    int k = t >> 1, hf = t & 1;
    float4 wr[18];
    float bh0 = 0.0f, bh1 = 0.0f, bh2 = 0.0f;
    if (t < 96) {
#pragma unroll
        for (int g = 0; g < 3; ++g) {
            const float4* q = reinterpret_cast<const float4*>(
                Whh + (g * KH + k) * KH + hf * 24);
#pragma unroll
            for (int j = 0; j < 6; ++j) wr[g * 6 + j] = q[j];
        }
        if (hf == 0) { bh0 = bhh[k]; bh1 = bhh[KH + k]; bh2 = bhh[2 * KH + k]; }
    }
    if (t < KH) s_h[t] = 0.0f;   // buffer 0
    float hk = 0.0f;
    for (int step = 0; step < T; ++step) {
        __syncthreads();
        int cur = step & 1, nxt = cur ^ 1;
        if (t < 96) {
            const float4* hp = reinterpret_cast<const float4*>(s_h + cur * KH)
                               + hf * 6;
            float a0 = bh0, a1 = bh1, a2 = bh2;
#pragma unroll
            for (int j = 0; j < 6; ++j) {
                float4 hv = hp[j];
                float4 w0 = wr[j], w1 = wr[6 + j], w2 = wr[12 + j];
                a0 += w0.x * hv.x + w0.y * hv.y + w0.z * hv.z + w0.w * hv.w;
                a1 += w1.x * hv.x + w1.y * hv.y + w1.z * hv.z + w1.w * hv.w;
                a2 += w2.x * hv.x + w2.y * hv.y + w2.z * hv.z + w2.w * hv.w;
            }
            a0 += __shfl_xor(a0, 1);
            a1 += __shfl_xor(a1, 1);
            a2 += __shfl_xor(a2, 1);
            if (hf == 0) {
                const float* gi = s_giA + step * G3;
                float r = sigmf(gi[k] + a0);
                float z = sigmf(gi[KH + k] + a1);
                float n = tanhfast(gi[2 * KH + k] + r * a2);
                hk = (1.0f - z) * n + z * hk;
                s_h[nxt * KH + k] = hk;
            }
        }
    }
    __syncthreads();
    if (t < KH) out48[t] = s_h[(T & 1) * KH + t];
}

// -------- recurrent-only GRU (gi precomputed in ws by k_edges1 prep) -------
__device__ void gru_rec(const float* giA /* [T][G3] global */, int T,
                        const float* Whh, const float* bhh,
                        float* out48, float* s_h /* [2][KH] */) {
    int t = threadIdx.x;
    int k = t >> 1, hf = t & 1;
    float4 wr[18];
    float bh0 = 0.0f, bh1 = 0.0f, bh2 = 0.0f;
    if (t < 96) {
#pragma unroll
        for (int g = 0; g < 3; ++g) {
            const float4* q = reinterpret_cast<const float4*>(
                Whh + (g * KH + k) * KH + hf * 24);
#pragma unroll
            for (int j = 0; j < 6; ++j) wr[g * 6 + j] = q[j];
        }
        if (hf == 0) { bh0 = bhh[k]; bh1 = bhh[KH + k]; bh2 = bhh[2 * KH + k]; }
    }
    if (t < KH) s_h[t] = 0.0f;
    float hk = 0.0f;
    for (int step = 0; step < T; ++step) {
        __syncthreads();
        int cur = step & 1, nxt = cur ^ 1;
        if (t < 96) {
            const float4* hp = reinterpret_cast<const float4*>(s_h + cur * KH)
                               + hf * 6;
            float a0 = bh0, a1 = bh1, a2 = bh2;
#pragma unroll
            for (int j = 0; j < 6; ++j) {
                float4 hv = hp[j];
                float4 w0 = wr[j], w1 = wr[6 + j], w2 = wr[12 + j];
                a0 += w0.x * hv.x + w0.y * hv.y + w0.z * hv.z + w0.w * hv.w;
                a1 += w1.x * hv.x + w1.y * hv.y + w1.z * hv.z + w1.w * hv.w;
                a2 += w2.x * hv.x + w2.y * hv.y + w2.z * hv.z + w2.w * hv.w;
            }
            a0 += __shfl_xor(a0, 1);
            a1 += __shfl_xor(a1, 1);
            a2 += __shfl_xor(a2, 1);
            if (hf == 0) {
                const float* gi = giA + step * G3;
                float r = sigmf(gi[k] + a0);
                float z = sigmf(gi[KH + k] + a1);
                float n = tanhfast(gi[2 * KH + k] + r * a2);
                hk = (1.0f - z) * n + z * hk;
                s_h[nxt * KH + k] = hk;
            }
        }
    }
    __syncthreads();
    if (t < KH) out48[t] = s_h[(T & 1) * KH + t];
}

// ---------------- K3: deg scan + all GRUs ----------------------------------
__global__ __launch_bounds__(192, 2) void k_gru(
    const float* x, const float* cpw, const float* cpb,
    const float* epWih, const float* epWhh, const float* epbih, const float* epbhh,
    const float* efWhh, const float* efbhh,
    const float* giP, const float* giF,
    const int* ei, const float* ew, const int* mark2, float* deg2,
    const int* s2, const unsigned* cnt, float* state, float* tpsf) {
    if (blockIdx.x < DEGB) {
        int per = NE / DEGB;
        int lo = blockIdx.x * per;
        for (int e = lo + threadIdx.x; e < lo + per; e += blockDim.x) {
            int c = ei[NE + e];
            int m = mark2[c];
            if (m > 0) atomicAdd(&deg2[m - 1], ew[e]);
        }
        return;
    }
    __shared__ __align__(16) float s_x[80];
    __shared__ __align__(16) float s_embed[40 * KH];
    __shared__ __align__(16) float s_giA[40 * G3];
    __shared__ __align__(16) float s_h[2 * KH];
    if (blockIdx.x == DEGB) {
        gru_rec(giP, 20, epWhh, epbhh, tpsf, s_h);
        return;
    }
    if (blockIdx.x == DEGB + 1) {
        gru_rec(giF, 40, efWhh, efbhh, tpsf + 64, s_h);
        return;
    }
    int b0 = blockIdx.x - (DEGB + 2);
    int nw = gridDim.x - (DEGB + 2);
    int cnt2 = (int)min(cnt[3], (unsigned)CAP_S2);
    for (int b = b0; b < cnt2; b += nw) {
        int node = s2[b];
        if (node < 0) continue;   // wasted CAS-loser slot
        gru_seq(x + (size_t)node * 40, 20, cpw, cpb, epWih, epWhh, epbih, epbhh,
                state + (size_t)b * KH, s_x, s_embed, s_giA, s_h);
    }
}

// ---------------- K4: gi0p (blocks 0..1, needs tpsf) + GCN L1 edge acc -----
__global__ void k_acc1(const unsigned* cnt, const int* e2r, const int* e2s,
                       const float* e2w, const int* mark2, const float* deg2,
                       const int* s1g, const float* state,
                       const float* W1, float* x1,
                       const float* dWih, const float* dbih, const float* tpsf,
                       float* gi0p) {
    if (blockIdx.x < GIB) {
        int row = blockIdx.x * blockDim.x + threadIdx.x;
        if (row < 432) {
            const float* wr = dWih + (size_t)row * G3;
            float acc = dbih[row];
#pragma unroll
            for (int m = 0; m < 48; ++m) acc += wr[48 + m] * tpsf[m];
#pragma unroll
            for (int m = 0; m < 48; ++m) acc += wr[96 + m] * tpsf[64 + m];
            gi0p[row] = acc;
        }
        return;
    }
    int nE = (int)min(cnt[2], (unsigned)CAP_E2);
    int total = nE * KH;
    int stride = (gridDim.x - GIB) * blockDim.x;
    for (int idx = (blockIdx.x - GIB) * blockDim.x + threadIdx.x; idx < total;
         idx += stride) {
        int e = idx / KH;
        int k = idx - e * KH;
        int row = e2r[e];
        int s2i = mark2[row] - 1;
        if (s2i < 0) continue;
        int cglob = s1g[e2s[e]];
        int cs2 = mark2[cglob] - 1;
        float norm = e2w[e] * rsqrtf(deg2[s2i] * deg2[cs2]);
        const float* sp = state + (size_t)s2i * KH;
        const float* wp = W1 + k * KH;
        float acc = 0.0f;
#pragma unroll
        for (int m = 0; m < KH; ++m) acc += sp[m] * wp[m];
        atomicAdd(&x1[e2s[e] * KH + k], acc * norm);
    }
}

// ---------------- K5: GCN layer 2 @ node 0 + decoder -----------------------
// R15 (= R14 resubmit after infra failure): R13's pin kept weights register-
// resident but the allocator held its ~128-VGPR occupancy target -> only ~16
// working regs -> serialized loop (43.9 -> 54.7). Fix the BUDGET:
// amdgpu_waves_per_eu(1,2) caps occupancy at 2 waves/EU -> 256-VGPR budget
// (6-wave block fits 2+2+1+1 on 4 SIMDs). Pin + 256 budget = 108 resident
// weight VGPRs + ~100 working regs with ILP.
__global__ __attribute__((amdgpu_waves_per_eu(1, 2))) __launch_bounds__(384)
void k_dec(
    const unsigned* cnt, const int* l1r, const float* l1w,
    const int* mark1, const int* mark2, const float* deg2, const float* x1,
    const float* W2, const float* b2, const float* tpsf, const float* past,
    const _Float16* whh16, const float* dwh4, const float* gi0p,
    const float* dbih, const float* dbhh,
    const float* fcw, const float* fcb, float* out) {
    __shared__ __align__(16) float s_conc[G3];
    __shared__ __align__(16) _Float16 s_h16[2][G3];   // fp16 h, double-buffered
    __shared__ __align__(16) float s_hf[2][G3];       // f32 h for fc
    int t = threadIdx.x;
    int k = t >> 1, hf = t & 1;
    // ---- hoisted Whh loads: one burst, pinned in registers ----
    h8_t wv[27];
    float bh[3] = {0.0f, 0.0f, 0.0f};
    float bi[3] = {0.0f, 0.0f, 0.0f};
#pragma unroll
    for (int c = 0; c < 27; ++c) wv[c] = (h8_t)(_Float16)0.0f;
    if (t < 288) {
        const h8_t* wp8 = reinterpret_cast<const h8_t*>(whh16);
#pragma unroll
        for (int c = 0; c < 27; ++c) wv[c] = wp8[c * 288 + t];
        if (hf == 0) {
#pragma unroll
            for (int g = 0; g < 3; ++g) {
                bh[g] = dbhh[g * G3 + k];
                bi[g] = dbih[g * G3 + k];
            }
        }
    }
#pragma unroll
    for (int c = 0; c < 27; ++c) asm volatile("" : "+v"(wv[c]));
    // fc wave preload (wave 5: threads 320..383)
    float fw0[3] = {0, 0, 0}, fw1[3] = {0, 0, 0};
    float fcb0 = 0.0f, fcb1 = 0.0f, pres0 = 0.0f, pres1 = 0.0f;
    if (t >= 320) {
        int lane = t - 320;
#pragma unroll
        for (int j = 0; j < 3; ++j) {
            int m = lane + 64 * j;
            if (m < G3) { fw0[j] = fcw[m]; fw1[j] = fcw[G3 + m]; }
        }
        if (lane == 0) {
            fcb0 = fcb[0]; fcb1 = fcb[1];
            pres0 = past[38]; pres1 = past[39];
        }
    }
    if (t < 48) s_conc[t] = b2[t];
    else if (t < 96) s_conc[t] = tpsf[t - 48];
    else if (t < 144) s_conc[t] = tpsf[64 + t - 96];
    if (t < G3) {
        s_h16[0][t] = (_Float16)0.0f;
        s_hf[0][t] = 0.0f;
    }
    __syncthreads();
    // layer-2 message accumulation into s_conc[0..47]
    int cl1 = (int)min(cnt[0], (unsigned)CAP_L1);
    float dinv0 = rsqrtf(deg2[mark2[0] - 1]);
    int items = (cl1 + 1) * KH;
    for (int idx = t; idx < items; idx += blockDim.x) {
        int e = idx / KH;
        int kk = idx - e * KH;
        int row; float norm;
        if (e == cl1) { row = 0; norm = dinv0 * dinv0; }
        else {
            row = l1r[e];
            int rs2 = mark2[row] - 1;
            if (rs2 < 0) continue;
            norm = l1w[e] * rsqrtf(deg2[rs2]) * dinv0;
        }
        int s1 = mark1[row] - 1;
        if (s1 < 0) continue;
        const float* xp = x1 + (size_t)s1 * KH;
        const float* wp = W2 + kk * KH;
        float acc = 0.0f;
#pragma unroll
        for (int m = 0; m < KH; ++m) acc += fmaxf(xp[m], 0.0f) * wp[m];
        atomicAdd(&s_conc[kk], acc * norm);
    }
    __syncthreads();   // s_conc complete
    // gi0: cols [hf*24, +24) x 3 gates, dWih head read directly (one-time)
    float gi0[3] = {0.0f, 0.0f, 0.0f};
    if (t < 288) {
        const float4* ccp = reinterpret_cast<const float4*>(s_conc) + hf * 6;
        float4 c0 = ccp[0], c1 = ccp[1], c2 = ccp[2];
        float4 c3 = ccp[3], c4 = ccp[4], c5 = ccp[5];
        const float4* dp = reinterpret_cast<const float4*>(dwh4);
#pragma unroll
        for (int g = 0; g < 3; ++g) {
            float4 w0 = dp[(g * 6 + 0) * 288 + t];
            float4 w1 = dp[(g * 6 + 1) * 288 + t];
            float4 w2 = dp[(g * 6 + 2) * 288 + t];
            float4 w3 = dp[(g * 6 + 3) * 288 + t];
            float4 w4 = dp[(g * 6 + 4) * 288 + t];
            float4 w5 = dp[(g * 6 + 5) * 288 + t];
            float acc = w0.x * c0.x + w0.y * c0.y + w0.z * c0.z + w0.w * c0.w;
            acc += w1.x * c1.x + w1.y * c1.y + w1.z * c1.z + w1.w * c1.w;
            acc += w2.x * c2.x + w2.y * c2.y + w2.z * c2.z + w2.w * c2.w;
            acc += w3.x * c3.x + w3.y * c3.y + w3.z * c3.z + w3.w * c3.w;
            acc += w4.x * c4.x + w4.y * c4.y + w4.z * c4.z + w4.w * c4.w;
            acc += w5.x * c5.x + w5.y * c5.y + w5.z * c5.z + w5.w * c5.w;
            acc += __shfl_xor(acc, 1);
            gi0[g] = acc + gi0p[g * G3 + k];
        }
    }
    float hk = 0.0f;   // h[k] carried in f32 (hf==0 lanes)
    for (int i = 0; i < 40; ++i) {
        __syncthreads();
        int cur = i & 1, nxt = cur ^ 1;
        if (t < 288) {
            // h half: 9 x ds_read_b128 (h8); wv consumed via aligned h2 halves
            const h8_t* hp = reinterpret_cast<const h8_t*>(&s_h16[cur][0]) + hf * 9;
            float a0 = bh[0], a1 = bh[1], a2 = bh[2];
#pragma unroll
            for (int j = 0; j < 9; ++j) {
                h8_t hv = hp[j];
                h2_t h0 = __builtin_shufflevector(hv, hv, 0, 1);
                h2_t h1 = __builtin_shufflevector(hv, hv, 2, 3);
                h2_t h2v = __builtin_shufflevector(hv, hv, 4, 5);
                h2_t h3 = __builtin_shufflevector(hv, hv, 6, 7);
                h8_t w0v = wv[j], w1v = wv[9 + j], w2v = wv[18 + j];
                a0 = fdot2f(__builtin_shufflevector(w0v, w0v, 0, 1), h0, a0);
                a1 = fdot2f(__builtin_shufflevector(w1v, w1v, 0, 1), h0, a1);
                a2 = fdot2f(__builtin_shufflevector(w2v, w2v, 0, 1), h0, a2);
                a0 = fdot2f(__builtin_shufflevector(w0v, w0v, 2, 3), h1, a0);
                a1 = fdot2f(__builtin_shufflevector(w1v, w1v, 2, 3), h1, a1);
                a2 = fdot2f(__builtin_shufflevector(w2v, w2v, 2, 3), h1, a2);
                a0 = fdot2f(__builtin_shufflevector(w0v, w0v, 4, 5), h2v, a0);
                a1 = fdot2f(__builtin_shufflevector(w1v, w1v, 4, 5), h2v, a1);
                a2 = fdot2f(__builtin_shufflevector(w2v, w2v, 4, 5), h2v, a2);
                a0 = fdot2f(__builtin_shufflevector(w0v, w0v, 6, 7), h3, a0);
                a1 = fdot2f(__builtin_shufflevector(w1v, w1v, 6, 7), h3, a1);
                a2 = fdot2f(__builtin_shufflevector(w2v, w2v, 6, 7), h3, a2);
            }
            a0 += __shfl_xor(a0, 1);
            a1 += __shfl_xor(a1, 1);
            a2 += __shfl_xor(a2, 1);
            if (hf == 0) {
                float gr = ((i == 0) ? gi0[0] : bi[0]) + a0;
                float gz = ((i == 0) ? gi0[1] : bi[1]) + a1;
                float gn = ((i == 0) ? gi0[2] : bi[2]);
                float r = sigmf(gr);
                float z = sigmf(gz);
                float n = tanhfast(gn + r * a2);
                hk = (1.0f - z) * n + z * hk;
                s_h16[nxt][k] = (_Float16)hk;
                s_hf[nxt][k] = hk;
            }
        } else if (t >= 320 && i >= 1) {
            int lane = t - 320;
            const float* hsrc = s_hf[cur];
            float p0 = 0.0f, p1 = 0.0f;
#pragma unroll
            for (int j = 0; j < 3; ++j) {
                int m = lane + 64 * j;
                if (m < G3) { float h = hsrc[m]; p0 += h * fw0[j]; p1 += h * fw1[j]; }
            }
#pragma unroll
            for (int off = 32; off > 0; off >>= 1) {
                p0 += __shfl_down(p0, off);
                p1 += __shfl_down(p1, off);
            }
            if (lane == 0) {
                pres0 += p0 + fcb0; pres1 += p1 + fcb1;
                out[(i - 1) * 2 + 0] = pres0;
                out[(i - 1) * 2 + 1] = pres1;
            }
        }
    }
    __syncthreads();
    if (t >= 320) {   // final step's fc (h_40 in buffer 0)
        int lane = t - 320;
        const float* hsrc = s_hf[0];
        float p0 = 0.0f, p1 = 0.0f;
#pragma unroll
        for (int j = 0; j < 3; ++j) {
            int m = lane + 64 * j;
            if (m < G3) { float h = hsrc[m]; p0 += h * fw0[j]; p1 += h * fw1[j]; }
        }
#pragma unroll
        for (int off = 32; off > 0; off >>= 1) {
            p0 += __shfl_down(p0, off);
            p1 += __shfl_down(p1, off);
        }
        if (lane == 0) {
            pres0 += p0 + fcb0; pres1 += p1 + fcb1;
            out[39 * 2 + 0] = pres0;
            out[39 * 2 + 1] = pres1;
        }
    }
}

extern "C" void kernel_launch(void* const* d_in, const int* in_sizes, int n_in,
                              void* d_out, int out_size, void* d_ws, size_t ws_size,
                              hipStream_t stream) {
    (void)in_sizes; (void)n_in; (void)out_size; (void)ws_size;
    const float* past   = (const float*)d_in[0];
    const float* future = (const float*)d_in[1];
    const float* x      = (const float*)d_in[2];
    const int*   ei     = (const int*)d_in[3];
    const float* ew     = (const float*)d_in[4];
    const float* cpw    = (const float*)d_in[5];
    const float* cpb    = (const float*)d_in[6];
    const float* cfw    = (const float*)d_in[7];
    const float* cfb    = (const float*)d_in[8];
    const float* epWih  = (const float*)d_in[9];
    const float* epWhh  = (const float*)d_in[10];
    const float* epbih  = (const float*)d_in[11];
    const float* epbhh  = (const float*)d_in[12];
    const float* efWih  = (const float*)d_in[13];
    const float* efWhh  = (const float*)d_in[14];
    const float* efbih  = (const float*)d_in[15];
    const float* efbhh  = (const float*)d_in[16];
    const float* dWih   = (const float*)d_in[17];
    const float* dWhh   = (const float*)d_in[18];
    const float* dbih   = (const float*)d_in[19];
    const float* dbhh   = (const float*)d_in[20];
    const float* fcw    = (const float*)d_in[21];
    const float* fcb    = (const float*)d_in[22];
    const float* g1w    = (const float*)d_in[23];
    const float* g1b    = (const float*)d_in[24];
    const float* g2w    = (const float*)d_in[25];
    const float* g2b    = (const float*)d_in[26];

    char* ws = (char*)d_ws;
    int*      mark1 = (int*)(ws + OFF_MARK1);
    int*      mark2 = (int*)(ws + OFF_MARK2);
    unsigned* cnt   = (unsigned*)(ws + OFF_CNT);
    int*      l1r   = (int*)(ws + OFF_L1R);
    float*    l1w   = (float*)(ws + OFF_L1W);
    int*      s1g   = (int*)(ws + OFF_S1G);
    int*      e2r   = (int*)(ws + OFF_E2R);
    int*      e2s   = (int*)(ws + OFF_E2S);
    float*    e2w   = (float*)(ws + OFF_E2W);
    int*      s2    = (int*)(ws + OFF_S2);
    float*    deg2  = (float*)(ws + OFF_DEG2);
    float*    state = (float*)(ws + OFF_STATE);
    float*    x1    = (float*)(ws + OFF_X1);
    float*    tpsf  = (float*)(ws + OFF_TPSF);
    _Float16* whh16 = (_Float16*)(ws + OFF_WHH16);
    float*    gi0p  = (float*)(ws + OFF_GI0P);
    float*    giP   = (float*)(ws + OFF_GIP);
    float*    giF   = (float*)(ws + OFF_GIF);
    float*    dwh4  = (float*)(ws + OFF_DWH4);

    hipMemsetAsync(ws, 0, 524352, stream);  // mark1 | mark2 | cnt
    k_edges1<<<E1B + PREPB, 256, 0, stream>>>(
        ei, ew, mark1, mark2, cnt, l1r, l1w, s1g, e2r, e2s, e2w,
        x1, g1b, s2, deg2,
        past, future, cpw, cpb, cfw, cfb,
        epWih, epbih, efWih, efbih, giP, giF);
    k_edges2<<<SB2 + E1B, 256, 0, stream>>>(ei, ew, mark1, mark2, cnt,
                                            e2r, e2s, e2w, s2, deg2,
                                            dWhh, dWih, whh16, dwh4);
    k_gru<<<DEGB + 2 + 512, 192, 0, stream>>>(x, cpw, cpb, epWih, epWhh, epbih, epbhh,
                                              efWhh, efbhh, giP, giF,
                                              ei, ew, mark2, deg2,
                                              s2, cnt, state, tpsf);
    k_acc1<<<GIB + 128, 256, 0, stream>>>(cnt, e2r, e2s, e2w, mark2, deg2, s1g,
                                          state, g1w, x1,
                                          dWih, dbih, tpsf, gi0p);
    k_dec<<<1, 384, 0, stream>>>(cnt, l1r, l1w, mark1, mark2, deg2, x1, g2w, g2b,
                                 tpsf, past, whh16, dwh4, gi0p, dbih, dbhh, fcw, fcb,
                                 (float*)d_out);
}

// Round 16
// 208.732 us; speedup vs baseline: 1.0172x; 1.0172x over previous
//
#include <hip/hip_runtime.h>
#include <math.h>

#define NN 65536
#define NE 1048576
#define KH 48
#define G3 144
#define DEGB 512
#define PREPB 15
#define E1B 1024      // edge-scan blocks (NE/4/256)
#define SB2 81        // staging blocks at head of k_edges2 (20736 ids)
#define GIB 2         // gi0p blocks at head of k_acc1

#define CAP_L1 8192
#define CAP_S1 4096
#define CAP_E2 65536
#define CAP_S2 8192

// ws byte offsets. First 524352 bytes (mark1|mark2|cnt) are zeroed by one
// hipMemsetAsync in kernel_launch.
#define OFF_MARK1  0u        // NN i32
#define OFF_MARK2  262144u   // NN i32
#define OFF_CNT    524288u   // 16 u32
#define OFF_L1R    524352u   // CAP_L1 i32
#define OFF_L1W    557120u   // CAP_L1 f32
#define OFF_S1G    589888u   // CAP_S1 i32
#define OFF_E2R    606272u   // CAP_E2 i32
#define OFF_E2S    868416u   // CAP_E2 i32
#define OFF_E2W    1130560u  // CAP_E2 f32
#define OFF_S2     1392704u  // CAP_S2 i32
#define OFF_DEG2   1425472u  // CAP_S2 f32
#define OFF_STATE  1458240u  // CAP_S2*48 f32
#define OFF_X1     3031104u  // CAP_S1*48 f32
#define OFF_TPSF   3817536u  // 128 f32
#define OFF_WHH16  3818048u  // fp16 dWhh, 288-thread h8 layout: 15552 h4 = 124416 B
#define OFF_GI0P   3947072u  // 432 f32
#define OFF_GIP    3948800u  // 20*144 f32
#define OFF_GIF    3960320u  // 40*144 f32
#define OFF_DWH4   3983360u  // 18*288 float4 (f32 dWih[:, :48], 288-thr layout) = 82944 B

typedef _Float16 h2_t __attribute__((ext_vector_type(2)));
typedef _Float16 h4_t __attribute__((ext_vector_type(4)));
typedef _Float16 h8_t __attribute__((ext_vector_type(8)));

// fast gates: v_exp_f32-based; error ~1e-6 rel, negligible vs fp16 weights
__device__ __forceinline__ float sigmf(float x) { return 1.0f / (1.0f + __expf(-x)); }
__device__ __forceinline__ float tanhfast(float x) {
    float e = __expf(2.0f * x);
    return 1.0f - 2.0f / (e + 1.0f);
}

#if __has_builtin(__builtin_amdgcn_fdot2)
__device__ __forceinline__ float fdot2f(h2_t a, h2_t b, float c) {
    return __builtin_amdgcn_fdot2(a, b, c, false);
}
#else
__device__ __forceinline__ float fdot2f(h2_t a, h2_t b, float c) {
    return c + (float)a.x * (float)b.x + (float)a.y * (float)b.y;
}
#endif

// -------- inline compaction (replaces old k_compact1/k_compact2) ----------
__device__ __forceinline__ void s2_append(int r, unsigned* cnt, int* mark2,
                                          int* s2, float* deg2) {
    if (mark2[r] != 0) return;            // benign stale-0 race: extra slot
    unsigned idx = atomicAdd(&cnt[3], 1u);
    if (idx >= CAP_S2) return;
    int old = atomicCAS(&mark2[r], 0, (int)idx + 1);
    deg2[idx] = 1.0f;
    s2[idx] = (old == 0) ? r : -1;        // -1: wasted slot, worker skips
}

__device__ __forceinline__ void s1_claim(int r, unsigned* cnt, int* mark1,
                                         int* mark2, int* s1g,
                                         int* e2r, int* e2s, float* e2w,
                                         float* x1, const float* g1b,
                                         int* s2, float* deg2) {
    if (mark1[r] != 0) return;
    unsigned idx = atomicAdd(&cnt[1], 1u);
    if (idx >= CAP_S1) return;
    int old = atomicCAS(&mark1[r], 0, (int)idx + 1);
    if (old != 0) return;                 // lost race; s1g[idx] stale, unread
    s1g[idx] = r;
    unsigned t2 = atomicAdd(&cnt[2], 1u); // self-loop E2 entry
    if (t2 < CAP_E2) { e2r[t2] = r; e2s[t2] = (int)idx; e2w[t2] = 1.0f; }
    for (int k = 0; k < KH; ++k) x1[idx * KH + k] = g1b[k];
    s2_append(r, cnt, mark2, s2, deg2);
}

// ---------------- K1: edges into node 0 + inline S1 compaction + prep ------
__global__ void k_edges1(const int* ei, const float* ew,
                         int* mark1, int* mark2, unsigned* cnt,
                         int* l1r, float* l1w, int* s1g,
                         int* e2r, int* e2s, float* e2w,
                         float* x1, const float* g1b, int* s2, float* deg2,
                         const float* past, const float* future,
                         const float* cpw, const float* cpb,
                         const float* cfw, const float* cfb,
                         const float* epWih, const float* epbih,
                         const float* efWih, const float* efbih,
                         float* giP, float* giF) {
    if (blockIdx.x >= E1B) {
        int p = blockIdx.x - E1B;   // 0..14
        const float* xs; const float* cw; const float* cb;
        const float* Wih; const float* bih; float* gout;
        int T, s0;
        if (p < 5) { xs = past;   cw = cpw; cb = cpb; Wih = epWih; bih = epbih;
                     gout = giP; T = 20; s0 = p * 4; }
        else       { xs = future; cw = cfw; cb = cfb; Wih = efWih; bih = efbih;
                     gout = giF; T = 40; s0 = (p - 5) * 4; }
        __shared__ __align__(16) float s_x[80];
        __shared__ __align__(16) float s_e[4 * KH];
        int t = threadIdx.x;
        if (t < T * 2) s_x[t] = xs[t];
        __syncthreads();
        for (int idx = t; idx < 4 * KH; idx += 256) {
            int lt = idx / KH;
            int k = idx - lt * KH;
            int tt = s0 + lt;
            float acc = cb[k];
#pragma unroll
            for (int d = 0; d < 3; ++d) {
                int tau = tt + d - 1;
                if (tau >= 0 && tau < T) {
                    acc += cw[k * 6 + d] * s_x[tau * 2 + 0];
                    acc += cw[k * 6 + 3 + d] * s_x[tau * 2 + 1];
                }
            }
            s_e[lt * KH + k] = fmaxf(acc, 0.0f);
        }
        __syncthreads();
        for (int idx = t; idx < 4 * G3; idx += 256) {
            int lt = idx / G3;
            int row = idx - lt * G3;
            const float4* wp = reinterpret_cast<const float4*>(Wih + row * KH);
            const float4* em = reinterpret_cast<const float4*>(s_e + lt * KH);
            float g = bih[row];
#pragma unroll
            for (int j = 0; j < 12; ++j) {
                float4 w4 = wp[j]; float4 e4 = em[j];
                g += w4.x * e4.x + w4.y * e4.y + w4.z * e4.z + w4.w * e4.w;
            }
            gout[(s0 + lt) * G3 + row] = g;
        }
        return;
    }
    int q = blockIdx.x * blockDim.x + threadIdx.x;
    if (q == 0)   // node 0 always in S1
        s1_claim(0, cnt, mark1, mark2, s1g, e2r, e2s, e2w, x1, g1b, s2, deg2);
    int4 c4 = reinterpret_cast<const int4*>(ei + NE)[q];
    int e = q * 4;
    int cc[4] = {c4.x, c4.y, c4.z, c4.w};
#pragma unroll
    for (int j = 0; j < 4; ++j) {
        if (cc[j] == 0) {
            int r = ei[e + j];
            float w = ew[e + j];
            unsigned s = atomicAdd(&cnt[0], 1u);
            if (s < CAP_L1) { l1r[s] = r; l1w[s] = w; }
            s1_claim(r, cnt, mark1, mark2, s1g, e2r, e2s, e2w, x1, g1b, s2, deg2);
        }
    }
}

// ---------------- K2: edges into S1 + inline S2 compaction + weight staging
__global__ void k_edges2(const int* ei, const float* ew,
                         const int* mark1, int* mark2, unsigned* cnt,
                         int* e2r, int* e2s, float* e2w, int* s2, float* deg2,
                         const float* dWhh, const float* dWih,
                         _Float16* whh16, float* dwh4) {
    if (blockIdx.x < SB2) {
        int id = blockIdx.x * blockDim.x + threadIdx.x;
        if (id < 27 * 288 * 2) {
            int pid = id >> 1, half = id & 1;
            int c = pid / 288, t = pid - c * 288;
            int k = t >> 1, hf = t & 1;
            int g = c / 9, u = c - g * 9;
            const float* src = dWhh + (size_t)(g * G3 + k) * G3
                               + hf * 72 + 8 * u + 4 * half;
            float4 f = *reinterpret_cast<const float4*>(src);
            h4_t o;
            o.x = (_Float16)f.x; o.y = (_Float16)f.y;
            o.z = (_Float16)f.z; o.w = (_Float16)f.w;
            reinterpret_cast<h4_t*>(whh16)[2 * pid + half] = o;
            return;
        }
        int id2 = id - 27 * 288 * 2;
        if (id2 < 18 * 288) {
            int c = id2 / 288, t = id2 - c * 288;
            int k = t >> 1, hf = t & 1;
            int g = c / 6, j = c - g * 6;
            const float* src = dWih + (size_t)(g * G3 + k) * G3 + hf * 24 + 4 * j;
            reinterpret_cast<float4*>(dwh4)[id2] =
                *reinterpret_cast<const float4*>(src);
        }
        return;
    }
    int q = (blockIdx.x - SB2) * blockDim.x + threadIdx.x;
    if (q >= NE / 4) return;
    int4 c4 = reinterpret_cast<const int4*>(ei + NE)[q];
    int e = q * 4;
    int cc[4] = {c4.x, c4.y, c4.z, c4.w};
#pragma unroll
    for (int j = 0; j < 4; ++j) {
        int m = mark1[cc[j]];
        if (m > 0) {
            int r = ei[e + j];
            float w = ew[e + j];
            unsigned s = atomicAdd(&cnt[2], 1u);
            if (s < CAP_E2) { e2r[s] = r; e2s[s] = m - 1; e2w[s] = w; }
            s2_append(r, cnt, mark2, s2, deg2);
        }
    }
}

// ---------------- conv1d(pad=1,k=3) + GRU over one sequence (S2 path) ------
__device__ void gru_seq(const float* xseq, int T,
                        const float* cw, const float* cb,
                        const float* Wih, const float* Whh,
                        const float* bih, const float* bhh,
                        float* out48,
                        float* s_x, float* s_embed, float* s_giA,
                        float* s_h /* [2][KH] */) {
    int t = threadIdx.x;
    int nt = blockDim.x;
    for (int i = t; i < T * 2; i += nt) s_x[i] = xseq[i];
    __syncthreads();
    for (int idx = t; idx < T * KH; idx += nt) {
        int tt = idx / KH;
        int k = idx - tt * KH;
        float acc = cb[k];
#pragma unroll
        for (int d = 0; d < 3; ++d) {
            int tau = tt + d - 1;
            if (tau >= 0 && tau < T) {
                acc += cw[k * 6 + d] * s_x[tau * 2 + 0];
                acc += cw[k * 6 + 3 + d] * s_x[tau * 2 + 1];
            }
        }
        s_embed[tt * KH + k] = fmaxf(acc, 0.0f);
    }
    __syncthreads();
    for (int idx = t; idx < T * G3; idx += nt) {
        int step = idx / G3;
        int row = idx - step * G3;
        const float4* wp = reinterpret_cast<const float4*>(Wih + row * KH);
        const float4* em = reinterpret_cast<const float4*>(s_embed + step * KH);
        float g = bih[row];
#pragma unroll
        for (int j = 0; j < 12; ++j) {
            float4 w4 = wp[j]; float4 e4 = em[j];
            g += w4.x * e4.x + w4.y * e4.y + w4.z * e4.z + w4.w * e4.w;
        }
        s_giA[idx] = g;
    }
    int k = t >> 1, hf = t & 1;
    float4 wr[18];
    float bh0 = 0.0f, bh1 = 0.0f, bh2 = 0.0f;
    if (t < 96) {
#pragma unroll
        for (int g = 0; g < 3; ++g) {
            const float4* q = reinterpret_cast<const float4*>(
                Whh + (g * KH + k) * KH + hf * 24);
#pragma unroll
            for (int j = 0; j < 6; ++j) wr[g * 6 + j] = q[j];
        }
        if (hf == 0) { bh0 = bhh[k]; bh1 = bhh[KH + k]; bh2 = bhh[2 * KH + k]; }
    }
    if (t < KH) s_h[t] = 0.0f;   // buffer 0
    float hk = 0.0f;
    for (int step = 0; step < T; ++step) {
        __syncthreads();
        int cur = step & 1, nxt = cur ^ 1;
        if (t < 96) {
            const float4* hp = reinterpret_cast<const float4*>(s_h + cur * KH)
                               + hf * 6;
            float a0 = bh0, a1 = bh1, a2 = bh2;
#pragma unroll
            for (int j = 0; j < 6; ++j) {
                float4 hv = hp[j];
                float4 w0 = wr[j], w1 = wr[6 + j], w2 = wr[12 + j];
                a0 += w0.x * hv.x + w0.y * hv.y + w0.z * hv.z + w0.w * hv.w;
                a1 += w1.x * hv.x + w1.y * hv.y + w1.z * hv.z + w1.w * hv.w;
                a2 += w2.x * hv.x + w2.y * hv.y + w2.z * hv.z + w2.w * hv.w;
            }
            a0 += __shfl_xor(a0, 1);
            a1 += __shfl_xor(a1, 1);
            a2 += __shfl_xor(a2, 1);
            if (hf == 0) {
                const float* gi = s_giA + step * G3;
                float r = sigmf(gi[k] + a0);
                float z = sigmf(gi[KH + k] + a1);
                float n = tanhfast(gi[2 * KH + k] + r * a2);
                hk = (1.0f - z) * n + z * hk;
                s_h[nxt * KH + k] = hk;
            }
        }
    }
    __syncthreads();
    if (t < KH) out48[t] = s_h[(T & 1) * KH + t];
}

// -------- recurrent-only GRU (gi precomputed in ws by k_edges1 prep) -------
__device__ void gru_rec(const float* giA /* [T][G3] global */, int T,
                        const float* Whh, const float* bhh,
                        float* out48, float* s_h /* [2][KH] */) {
    int t = threadIdx.x;
    int k = t >> 1, hf = t & 1;
    float4 wr[18];
    float bh0 = 0.0f, bh1 = 0.0f, bh2 = 0.0f;
    if (t < 96) {
#pragma unroll
        for (int g = 0; g < 3; ++g) {
            const float4* q = reinterpret_cast<const float4*>(
                Whh + (g * KH + k) * KH + hf * 24);
#pragma unroll
            for (int j = 0; j < 6; ++j) wr[g * 6 + j] = q[j];
        }
        if (hf == 0) { bh0 = bhh[k]; bh1 = bhh[KH + k]; bh2 = bhh[2 * KH + k]; }
    }
    if (t < KH) s_h[t] = 0.0f;
    float hk = 0.0f;
    for (int step = 0; step < T; ++step) {
        __syncthreads();
        int cur = step & 1, nxt = cur ^ 1;
        if (t < 96) {
            const float4* hp = reinterpret_cast<const float4*>(s_h + cur * KH)
                               + hf * 6;
            float a0 = bh0, a1 = bh1, a2 = bh2;
#pragma unroll
            for (int j = 0; j < 6; ++j) {
                float4 hv = hp[j];
                float4 w0 = wr[j], w1 = wr[6 + j], w2 = wr[12 + j];
                a0 += w0.x * hv.x + w0.y * hv.y + w0.z * hv.z + w0.w * hv.w;
                a1 += w1.x * hv.x + w1.y * hv.y + w1.z * hv.z + w1.w * hv.w;
                a2 += w2.x * hv.x + w2.y * hv.y + w2.z * hv.z + w2.w * hv.w;
            }
            a0 += __shfl_xor(a0, 1);
            a1 += __shfl_xor(a1, 1);
            a2 += __shfl_xor(a2, 1);
            if (hf == 0) {
                const float* gi = giA + step * G3;
                float r = sigmf(gi[k] + a0);
                float z = sigmf(gi[KH + k] + a1);
                float n = tanhfast(gi[2 * KH + k] + r * a2);
                hk = (1.0f - z) * n + z * hk;
                s_h[nxt * KH + k] = hk;
            }
        }
    }
    __syncthreads();
    if (t < KH) out48[t] = s_h[(T & 1) * KH + t];
}

// ---------------- K3: deg scan + all GRUs ----------------------------------
__global__ __launch_bounds__(192, 2) void k_gru(
    const float* x, const float* cpw, const float* cpb,
    const float* epWih, const float* epWhh, const float* epbih, const float* epbhh,
    const float* efWhh, const float* efbhh,
    const float* giP, const float* giF,
    const int* ei, const float* ew, const int* mark2, float* deg2,
    const int* s2, const unsigned* cnt, float* state, float* tpsf) {
    if (blockIdx.x < DEGB) {
        int per = NE / DEGB;
        int lo = blockIdx.x * per;
        for (int e = lo + threadIdx.x; e < lo + per; e += blockDim.x) {
            int c = ei[NE + e];
            int m = mark2[c];
            if (m > 0) atomicAdd(&deg2[m - 1], ew[e]);
        }
        return;
    }
    __shared__ __align__(16) float s_x[80];
    __shared__ __align__(16) float s_embed[40 * KH];
    __shared__ __align__(16) float s_giA[40 * G3];
    __shared__ __align__(16) float s_h[2 * KH];
    if (blockIdx.x == DEGB) {
        gru_rec(giP, 20, epWhh, epbhh, tpsf, s_h);
        return;
    }
    if (blockIdx.x == DEGB + 1) {
        gru_rec(giF, 40, efWhh, efbhh, tpsf + 64, s_h);
        return;
    }
    int b0 = blockIdx.x - (DEGB + 2);
    int nw = gridDim.x - (DEGB + 2);
    int cnt2 = (int)min(cnt[3], (unsigned)CAP_S2);
    for (int b = b0; b < cnt2; b += nw) {
        int node = s2[b];
        if (node < 0) continue;   // wasted CAS-loser slot
        gru_seq(x + (size_t)node * 40, 20, cpw, cpb, epWih, epWhh, epbih, epbhh,
                state + (size_t)b * KH, s_x, s_embed, s_giA, s_h);
    }
}

// ---------------- K4: gi0p (blocks 0..1, needs tpsf) + GCN L1 edge acc -----
__global__ void k_acc1(const unsigned* cnt, const int* e2r, const int* e2s,
                       const float* e2w, const int* mark2, const float* deg2,
                       const int* s1g, const float* state,
                       const float* W1, float* x1,
                       const float* dWih, const float* dbih, const float* tpsf,
                       float* gi0p) {
    if (blockIdx.x < GIB) {
        int row = blockIdx.x * blockDim.x + threadIdx.x;
        if (row < 432) {
            const float* wr = dWih + (size_t)row * G3;
            float acc = dbih[row];
#pragma unroll
            for (int m = 0; m < 48; ++m) acc += wr[48 + m] * tpsf[m];
#pragma unroll
            for (int m = 0; m < 48; ++m) acc += wr[96 + m] * tpsf[64 + m];
            gi0p[row] = acc;
        }
        return;
    }
    int nE = (int)min(cnt[2], (unsigned)CAP_E2);
    int total = nE * KH;
    int stride = (gridDim.x - GIB) * blockDim.x;
    for (int idx = (blockIdx.x - GIB) * blockDim.x + threadIdx.x; idx < total;
         idx += stride) {
        int e = idx / KH;
        int k = idx - e * KH;
        int row = e2r[e];
        int s2i = mark2[row] - 1;
        if (s2i < 0) continue;
        int cglob = s1g[e2s[e]];
        int cs2 = mark2[cglob] - 1;
        float norm = e2w[e] * rsqrtf(deg2[s2i] * deg2[cs2]);
        const float* sp = state + (size_t)s2i * KH;
        const float* wp = W1 + k * KH;
        float acc = 0.0f;
#pragma unroll
        for (int m = 0; m < KH; ++m) acc += sp[m] * wp[m];
        atomicAdd(&x1[e2s[e] * KH + k], acc * norm);
    }
}

// ---------------- K5: GCN layer 2 @ node 0 + decoder (R11 = best) ----------
// R16: revert to R11's exact k_dec (burst hoist, NO asm pin, no waves_per_eu
// attr) — best measured at 43.3-43.9us. R13/R15's pin forced weights live
// but the allocator kept its 124-reg target -> ~16 working regs -> 54.7us.
// R15 showed amdgpu_waves_per_eu is ignored here. Six variants bracket
// ~44us as this structure's single-CU serial-recurrence floor.
__global__ __launch_bounds__(384, 1) void k_dec(
    const unsigned* cnt, const int* l1r, const float* l1w,
    const int* mark1, const int* mark2, const float* deg2, const float* x1,
    const float* W2, const float* b2, const float* tpsf, const float* past,
    const _Float16* whh16, const float* dwh4, const float* gi0p,
    const float* dbih, const float* dbhh,
    const float* fcw, const float* fcb, float* out) {
    __shared__ __align__(16) float s_conc[G3];
    __shared__ __align__(16) _Float16 s_h16[2][G3];   // fp16 h, double-buffered
    __shared__ __align__(16) float s_hf[2][G3];       // f32 h for fc
    int t = threadIdx.x;
    int k = t >> 1, hf = t & 1;
    // ---- hoisted weight loads: one burst, consumed after conc phase ----
    h8_t wv[27];
    float4 dv[18];
    float bh[3] = {0.0f, 0.0f, 0.0f};
    float bi[3] = {0.0f, 0.0f, 0.0f};
#pragma unroll
    for (int c = 0; c < 27; ++c) wv[c] = (h8_t)(_Float16)0.0f;
#pragma unroll
    for (int c = 0; c < 18; ++c) dv[c] = make_float4(0.f, 0.f, 0.f, 0.f);
    if (t < 288) {
        const h8_t* wp8 = reinterpret_cast<const h8_t*>(whh16);
#pragma unroll
        for (int c = 0; c < 27; ++c) wv[c] = wp8[c * 288 + t];
        const float4* dp = reinterpret_cast<const float4*>(dwh4);
#pragma unroll
        for (int c = 0; c < 18; ++c) dv[c] = dp[c * 288 + t];
        if (hf == 0) {
#pragma unroll
            for (int g = 0; g < 3; ++g) {
                bh[g] = dbhh[g * G3 + k];
                bi[g] = dbih[g * G3 + k];
            }
        }
    }
    // fc wave preload (wave 5: threads 320..383)
    float fw0[3] = {0, 0, 0}, fw1[3] = {0, 0, 0};
    float fcb0 = 0.0f, fcb1 = 0.0f, pres0 = 0.0f, pres1 = 0.0f;
    if (t >= 320) {
        int lane = t - 320;
#pragma unroll
        for (int j = 0; j < 3; ++j) {
            int m = lane + 64 * j;
            if (m < G3) { fw0[j] = fcw[m]; fw1[j] = fcw[G3 + m]; }
        }
        if (lane == 0) {
            fcb0 = fcb[0]; fcb1 = fcb[1];
            pres0 = past[38]; pres1 = past[39];
        }
    }
    if (t < 48) s_conc[t] = b2[t];
    else if (t < 96) s_conc[t] = tpsf[t - 48];
    else if (t < 144) s_conc[t] = tpsf[64 + t - 96];
    if (t < G3) {
        s_h16[0][t] = (_Float16)0.0f;
        s_hf[0][t] = 0.0f;
    }
    __syncthreads();
    // layer-2 message accumulation into s_conc[0..47] (overlaps weight fetch)
    int cl1 = (int)min(cnt[0], (unsigned)CAP_L1);
    float dinv0 = rsqrtf(deg2[mark2[0] - 1]);
    int items = (cl1 + 1) * KH;
    for (int idx = t; idx < items; idx += blockDim.x) {
        int e = idx / KH;
        int kk = idx - e * KH;
        int row; float norm;
        if (e == cl1) { row = 0; norm = dinv0 * dinv0; }
        else {
            row = l1r[e];
            int rs2 = mark2[row] - 1;
            if (rs2 < 0) continue;
            norm = l1w[e] * rsqrtf(deg2[rs2]) * dinv0;
        }
        int s1 = mark1[row] - 1;
        if (s1 < 0) continue;
        const float* xp = x1 + (size_t)s1 * KH;
        const float* wp = W2 + kk * KH;
        float acc = 0.0f;
#pragma unroll
        for (int m = 0; m < KH; ++m) acc += fmaxf(xp[m], 0.0f) * wp[m];
        atomicAdd(&s_conc[kk], acc * norm);
    }
    __syncthreads();   // s_conc complete
    // gi0: cols [hf*24, +24) x 3 gates from hoisted dv + shfl_xor(1)
    float gi0[3] = {0.0f, 0.0f, 0.0f};
    if (t < 288) {
        const float4* ccp = reinterpret_cast<const float4*>(s_conc) + hf * 6;
        float4 c0 = ccp[0], c1 = ccp[1], c2 = ccp[2];
        float4 c3 = ccp[3], c4 = ccp[4], c5 = ccp[5];
#pragma unroll
        for (int g = 0; g < 3; ++g) {
            float4 w0 = dv[g * 6 + 0], w1 = dv[g * 6 + 1], w2 = dv[g * 6 + 2];
            float4 w3 = dv[g * 6 + 3], w4 = dv[g * 6 + 4], w5 = dv[g * 6 + 5];
            float acc = w0.x * c0.x + w0.y * c0.y + w0.z * c0.z + w0.w * c0.w;
            acc += w1.x * c1.x + w1.y * c1.y + w1.z * c1.z + w1.w * c1.w;
            acc += w2.x * c2.x + w2.y * c2.y + w2.z * c2.z + w2.w * c2.w;
            acc += w3.x * c3.x + w3.y * c3.y + w3.z * c3.z + w3.w * c3.w;
            acc += w4.x * c4.x + w4.y * c4.y + w4.z * c4.z + w4.w * c4.w;
            acc += w5.x * c5.x + w5.y * c5.y + w5.z * c5.z + w5.w * c5.w;
            acc += __shfl_xor(acc, 1);
            gi0[g] = acc + gi0p[g * G3 + k];
        }
    }
    float hk = 0.0f;   // h[k] carried in f32 (hf==0 lanes)
    for (int i = 0; i < 40; ++i) {
        __syncthreads();
        int cur = i & 1, nxt = cur ^ 1;
        if (t < 288) {
            // h half: 9 x ds_read_b128 (h8), weights consumed via subregister
            const h8_t* hp = reinterpret_cast<const h8_t*>(&s_h16[cur][0]) + hf * 9;
            float a0 = bh[0], a1 = bh[1], a2 = bh[2];
#pragma unroll
            for (int j = 0; j < 9; ++j) {
                h8_t hv = hp[j];
                h2_t h0 = __builtin_shufflevector(hv, hv, 0, 1);
                h2_t h1 = __builtin_shufflevector(hv, hv, 2, 3);
                h2_t h2v = __builtin_shufflevector(hv, hv, 4, 5);
                h2_t h3 = __builtin_shufflevector(hv, hv, 6, 7);
                h8_t w0v = wv[j], w1v = wv[9 + j], w2v = wv[18 + j];
                a0 = fdot2f(__builtin_shufflevector(w0v, w0v, 0, 1), h0, a0);
                a1 = fdot2f(__builtin_shufflevector(w1v, w1v, 0, 1), h0, a1);
                a2 = fdot2f(__builtin_shufflevector(w2v, w2v, 0, 1), h0, a2);
                a0 = fdot2f(__builtin_shufflevector(w0v, w0v, 2, 3), h1, a0);
                a1 = fdot2f(__builtin_shufflevector(w1v, w1v, 2, 3), h1, a1);
                a2 = fdot2f(__builtin_shufflevector(w2v, w2v, 2, 3), h1, a2);
                a0 = fdot2f(__builtin_shufflevector(w0v, w0v, 4, 5), h2v, a0);
                a1 = fdot2f(__builtin_shufflevector(w1v, w1v, 4, 5), h2v, a1);
                a2 = fdot2f(__builtin_shufflevector(w2v, w2v, 4, 5), h2v, a2);
                a0 = fdot2f(__builtin_shufflevector(w0v, w0v, 6, 7), h3, a0);
                a1 = fdot2f(__builtin_shufflevector(w1v, w1v, 6, 7), h3, a1);
                a2 = fdot2f(__builtin_shufflevector(w2v, w2v, 6, 7), h3, a2);
            }
            a0 += __shfl_xor(a0, 1);
            a1 += __shfl_xor(a1, 1);
            a2 += __shfl_xor(a2, 1);
            if (hf == 0) {
                float gr = ((i == 0) ? gi0[0] : bi[0]) + a0;
                float gz = ((i == 0) ? gi0[1] : bi[1]) + a1;
                float gn = ((i == 0) ? gi0[2] : bi[2]);
                float r = sigmf(gr);
                float z = sigmf(gz);
                float n = tanhfast(gn + r * a2);
                hk = (1.0f - z) * n + z * hk;
                s_h16[nxt][k] = (_Float16)hk;
                s_hf[nxt][k] = hk;
            }
        } else if (t >= 320 && i >= 1) {
            int lane = t - 320;
            const float* hsrc = s_hf[cur];
            float p0 = 0.0f, p1 = 0.0f;
#pragma unroll
            for (int j = 0; j < 3; ++j) {
                int m = lane + 64 * j;
                if (m < G3) { float h = hsrc[m]; p0 += h * fw0[j]; p1 += h * fw1[j]; }
            }
#pragma unroll
            for (int off = 32; off > 0; off >>= 1) {
                p0 += __shfl_down(p0, off);
                p1 += __shfl_down(p1, off);
            }
            if (lane == 0) {
                pres0 += p0 + fcb0; pres1 += p1 + fcb1;
                out[(i - 1) * 2 + 0] = pres0;
                out[(i - 1) * 2 + 1] = pres1;
            }
        }
    }
    __syncthreads();
    if (t >= 320) {   // final step's fc (h_40 in buffer 0)
        int lane = t - 320;
        const float* hsrc = s_hf[0];
        float p0 = 0.0f, p1 = 0.0f;
#pragma unroll
        for (int j = 0; j < 3; ++j) {
            int m = lane + 64 * j;
            if (m < G3) { float h = hsrc[m]; p0 += h * fw0[j]; p1 += h * fw1[j]; }
        }
#pragma unroll
        for (int off = 32; off > 0; off >>= 1) {
            p0 += __shfl_down(p0, off);
            p1 += __shfl_down(p1, off);
        }
        if (lane == 0) {
            pres0 += p0 + fcb0; pres1 += p1 + fcb1;
            out[39 * 2 + 0] = pres0;
            out[39 * 2 + 1] = pres1;
        }
    }
}

extern "C" void kernel_launch(void* const* d_in, const int* in_sizes, int n_in,
                              void* d_out, int out_size, void* d_ws, size_t ws_size,
                              hipStream_t stream) {
    (void)in_sizes; (void)n_in; (void)out_size; (void)ws_size;
    const float* past   = (const float*)d_in[0];
    const float* future = (const float*)d_in[1];
    const float* x      = (const float*)d_in[2];
    const int*   ei     = (const int*)d_in[3];
    const float* ew     = (const float*)d_in[4];
    const float* cpw    = (const float*)d_in[5];
    const float* cpb    = (const float*)d_in[6];
    const float* cfw    = (const float*)d_in[7];
    const float* cfb    = (const float*)d_in[8];
    const float* epWih  = (const float*)d_in[9];
    const float* epWhh  = (const float*)d_in[10];
    const float* epbih  = (const float*)d_in[11];
    const float* epbhh  = (const float*)d_in[12];
    const float* efWih  = (const float*)d_in[13];
    const float* efWhh  = (const float*)d_in[14];
    const float* efbih  = (const float*)d_in[15];
    const float* efbhh  = (const float*)d_in[16];
    const float* dWih   = (const float*)d_in[17];
    const float* dWhh   = (const float*)d_in[18];
    const float* dbih   = (const float*)d_in[19];
    const float* dbhh   = (const float*)d_in[20];
    const float* fcw    = (const float*)d_in[21];
    const float* fcb    = (const float*)d_in[22];
    const float* g1w    = (const float*)d_in[23];
    const float* g1b    = (const float*)d_in[24];
    const float* g2w    = (const float*)d_in[25];
    const float* g2b    = (const float*)d_in[26];

    char* ws = (char*)d_ws;
    int*      mark1 = (int*)(ws + OFF_MARK1);
    int*      mark2 = (int*)(ws + OFF_MARK2);
    unsigned* cnt   = (unsigned*)(ws + OFF_CNT);
    int*      l1r   = (int*)(ws + OFF_L1R);
    float*    l1w   = (float*)(ws + OFF_L1W);
    int*      s1g   = (int*)(ws + OFF_S1G);
    int*      e2r   = (int*)(ws + OFF_E2R);
    int*      e2s   = (int*)(ws + OFF_E2S);
    float*    e2w   = (float*)(ws + OFF_E2W);
    int*      s2    = (int*)(ws + OFF_S2);
    float*    deg2  = (float*)(ws + OFF_DEG2);
    float*    state = (float*)(ws + OFF_STATE);
    float*    x1    = (float*)(ws + OFF_X1);
    float*    tpsf  = (float*)(ws + OFF_TPSF);
    _Float16* whh16 = (_Float16*)(ws + OFF_WHH16);
    float*    gi0p  = (float*)(ws + OFF_GI0P);
    float*    giP   = (float*)(ws + OFF_GIP);
    float*    giF   = (float*)(ws + OFF_GIF);
    float*    dwh4  = (float*)(ws + OFF_DWH4);

    hipMemsetAsync(ws, 0, 524352, stream);  // mark1 | mark2 | cnt
    k_edges1<<<E1B + PREPB, 256, 0, stream>>>(
        ei, ew, mark1, mark2, cnt, l1r, l1w, s1g, e2r, e2s, e2w,
        x1, g1b, s2, deg2,
        past, future, cpw, cpb, cfw, cfb,
        epWih, epbih, efWih, efbih, giP, giF);
    k_edges2<<<SB2 + E1B, 256, 0, stream>>>(ei, ew, mark1, mark2, cnt,
                                            e2r, e2s, e2w, s2, deg2,
                                            dWhh, dWih, whh16, dwh4);
    k_gru<<<DEGB + 2 + 512, 192, 0, stream>>>(x, cpw, cpb, epWih, epWhh, epbih, epbhh,
                                              efWhh, efbhh, giP, giF,
                                              ei, ew, mark2, deg2,
                                              s2, cnt, state, tpsf);
    k_acc1<<<GIB + 128, 256, 0, stream>>>(cnt, e2r, e2s, e2w, mark2, deg2, s1g,
                                          state, g1w, x1,
                                          dWih, dbih, tpsf, gi0p);
    k_dec<<<1, 384, 0, stream>>>(cnt, l1r, l1w, mark1, mark2, deg2, x1, g2w, g2b,
                                 tpsf, past, whh16, dwh4, gi0p, dbih, dbhh, fcw, fcb,
                                 (float*)d_out);
}